// Round 3
// baseline (327.448 us; speedup 1.0000x reference)
//
#include <hip/hip_runtime.h>
#include <hip/hip_cooperative_groups.h>
#include <hip/hip_bf16.h>
#include <cstddef>

namespace cg = cooperative_groups;

#define NNODE 4096
#define INF   512
#define OUTF  256
#define HID   8
#define CAP   128   // max degree; Binomial(4096,0.01) max ~67
#define NB    256   // 1 block per CU -> cooperative co-residency guaranteed
#define NT    512   // 8 waves per block

typedef __attribute__((ext_vector_type(8))) short short8;
typedef __attribute__((ext_vector_type(4))) float f32x4;

__device__ __forceinline__ unsigned short f2bf(float f){
  unsigned int u = __float_as_uint(f);
  u += 0x7fffu + ((u >> 16) & 1u);   // RNE
  return (unsigned short)(u >> 16);
}
__device__ __forceinline__ float bf2f(unsigned short s){
  return __uint_as_float(((unsigned int)s) << 16);
}

struct KParams {
  const float* x; const float* adj; const float* W1; const float* a1;
  const float* W2; const float* a2; const float* Wsgc; const float* bsgc;
  float* out;
  int* deg; int* cols; float* h; float* dstv; float* h2; float* maskf;
  unsigned short* xb; unsigned short* wbT; unsigned short* G;
  unsigned short* T1; unsigned short* T2;
};

// gather sum of bf16 row-segments (4 cols per lane), unroll-8 for MLP
__device__ __forceinline__ f32x4 gather_row(const unsigned short* __restrict__ src,
                                            int stride, const int* __restrict__ cl,
                                            int d, int lane){
  f32x4 acc = {0.f, 0.f, 0.f, 0.f};
  int n = 0;
  for (; n + 8 <= d; n += 8){
    ushort4 v[8];
    #pragma unroll
    for (int u = 0; u < 8; u++){
      int j = cl[n + u];
      v[u] = *(const ushort4*)(src + (size_t)j * stride + lane * 4);
    }
    #pragma unroll
    for (int u = 0; u < 8; u++){
      acc[0] += bf2f(v[u].x); acc[1] += bf2f(v[u].y);
      acc[2] += bf2f(v[u].z); acc[3] += bf2f(v[u].w);
    }
  }
  for (; n < d; n++){
    int j = cl[n];
    ushort4 vv = *(const ushort4*)(src + (size_t)j * stride + lane * 4);
    acc[0] += bf2f(vv.x); acc[1] += bf2f(vv.y); acc[2] += bf2f(vv.z); acc[3] += bf2f(vv.w);
  }
  return acc;
}

__device__ __forceinline__ void store_bf4(unsigned short* dst, f32x4 a){
  union { ushort4 v; unsigned short u[4]; } o;
  o.u[0] = f2bf(a[0]); o.u[1] = f2bf(a[1]); o.u[2] = f2bf(a[2]); o.u[3] = f2bf(a[3]);
  *(ushort4*)dst = o.v;
}

__global__ __launch_bounds__(NT, 2) void fused_all(KParams P){
  cg::grid_group grid = cg::this_grid();
  __shared__ __align__(16) char smem[27648];   // max(GEMM tiles 27.6KB, softmax 16KB)
  __shared__ float red[8];
  __shared__ int cnts[16];
  const int tid = threadIdx.x, lane = tid & 63, wv = tid >> 6;
  const int b = blockIdx.x, rowBase = b * 16;

  // ======================= P0: CSR + converts + gat_h =======================
  if (tid < 16) cnts[tid] = 0;
  __syncthreads();

  // W' -> bf16 transposed:  wbT[c][k];  W'[k][c<256]=Wsgc[k][c], else Wsgc[1024+k][c-256]
  #pragma unroll
  for (int t = 0; t < 2; t++){
    int e = t * (NB * NT) + b * NT + tid;     // 0..262143
    int c = e >> 9, k = e & 511;
    float val = (c < OUTF) ? P.Wsgc[(size_t)k * OUTF + c]
                           : P.Wsgc[(size_t)(1024 + k) * OUTF + (c - OUTF)];
    P.wbT[e] = f2bf(val);
  }
  // x -> bf16 (16 rows per block)
  #pragma unroll
  for (int t = 0; t < 2; t++){
    int g = t * NT + tid;                     // 0..1023 groups of 8
    int r = g >> 6, ko = (g & 63) * 8;
    const float* src = P.x + (size_t)(rowBase + r) * INF + ko;
    float4 v0 = ((const float4*)src)[0];
    float4 v1 = ((const float4*)src)[1];
    union { short8 v; unsigned short u[8]; } pk;
    pk.u[0]=f2bf(v0.x); pk.u[1]=f2bf(v0.y); pk.u[2]=f2bf(v0.z); pk.u[3]=f2bf(v0.w);
    pk.u[4]=f2bf(v1.x); pk.u[5]=f2bf(v1.y); pk.u[6]=f2bf(v1.z); pk.u[7]=f2bf(v1.w);
    *(short8*)(P.xb + (size_t)(rowBase + r) * INF + ko) = pk.v;
  }
  // gat_h: h = x@W1, dstv = h . a1[8:16]  (fp32, wave per row, 2 rows/wave)
  for (int rr = 0; rr < 2; rr++){
    int row = rowBase + wv * 2 + rr;
    const float* xr = P.x + (size_t)row * INF;
    float acc[HID];
    #pragma unroll
    for (int f = 0; f < HID; f++) acc[f] = 0.f;
    for (int k = lane; k < INF; k += 64){
      float xv = xr[k];
      const float* wp = P.W1 + (size_t)k * HID;
      #pragma unroll
      for (int f = 0; f < HID; f++) acc[f] += xv * wp[f];
    }
    #pragma unroll
    for (int f = 0; f < HID; f++)
      for (int o = 32; o >= 1; o >>= 1) acc[f] += __shfl_xor(acc[f], o, 64);
    if (lane == 0){
      float d = 0.f;
      #pragma unroll
      for (int f = 0; f < HID; f++){ P.h[(size_t)row*HID + f] = acc[f]; d += acc[f] * P.a1[HID + f]; }
      P.dstv[row] = d;
    }
  }
  // CSR: wave scans its 2 rows (order of neighbors irrelevant: all consumers sum)
  for (int rr = 0; rr < 2; rr++){
    int lrow = wv * 2 + rr, row = rowBase + lrow;
    const float4* arow = (const float4*)(P.adj + (size_t)row * NNODE);
    int* crow = P.cols + (size_t)row * CAP;
    for (int kk = 0; kk < 16; kk++){
      int idx = kk * 64 + lane;
      float4 v = arow[idx];
      int n0=(v.x!=0.f), n1=(v.y!=0.f), n2=(v.z!=0.f), n3=(v.w!=0.f);
      int m = n0 + n1 + n2 + n3;
      if (m){
        int base = atomicAdd(&cnts[lrow], m);
        int c = idx * 4;
        if (n0){ if (base < CAP) crow[base] = c;     base++; }
        if (n1){ if (base < CAP) crow[base] = c + 1; base++; }
        if (n2){ if (base < CAP) crow[base] = c + 2; base++; }
        if (n3){ if (base < CAP) crow[base] = c + 3; }
      }
    }
  }
  __syncthreads();
  if (tid < 16) P.deg[rowBase + tid] = cnts[tid] > CAP ? CAP : cnts[tid];
  grid.sync();

  // ======================= P1: GEMM  G = xb @ W'  (bf16 MFMA) ===============
  {
    unsigned short (*As)[72] = (unsigned short (*)[72])smem;          // 128 x 64 (+8 pad)
    unsigned short (*Bs)[72] = (unsigned short (*)[72])(smem + 128*72*2); // 64 x 64
    int row0 = (b >> 3) * 128;
    int col0 = (b & 7) * 64;
    int wr = wv >> 1, wc = wv & 1;     // 4x2 wave grid, each wave 32x32 out
    f32x4 acc[2][2];
    #pragma unroll
    for (int i = 0; i < 2; i++)
      #pragma unroll
      for (int j = 0; j < 2; j++)
        #pragma unroll
        for (int e = 0; e < 4; e++) acc[i][j][e] = 0.f;
    int mrow = lane & 15;
    int kq = (lane >> 4) * 8;
    for (int k0 = 0; k0 < 512; k0 += 64){
      #pragma unroll
      for (int t = 0; t < 2; t++){     // stage A: 1024 int4s / 512 threads
        int id = t * NT + tid;
        int r = id >> 3, ko = (id & 7) * 8;
        *(int4*)(&As[r][ko]) = *(const int4*)(P.xb + (size_t)(row0 + r) * 512 + k0 + ko);
      }
      { int c = tid >> 3, ko = (tid & 7) * 8;   // stage B: 512 int4s
        *(int4*)(&Bs[c][ko]) = *(const int4*)(P.wbT + (size_t)(col0 + c) * 512 + k0 + ko); }
      __syncthreads();
      #pragma unroll
      for (int kk = 0; kk < 2; kk++){
        short8 a0 = *(const short8*)(&As[wr*32 +  0 + mrow][kk*32 + kq]);
        short8 a1 = *(const short8*)(&As[wr*32 + 16 + mrow][kk*32 + kq]);
        short8 b0 = *(const short8*)(&Bs[wc*32 +  0 + mrow][kk*32 + kq]);
        short8 b1 = *(const short8*)(&Bs[wc*32 + 16 + mrow][kk*32 + kq]);
        acc[0][0] = __builtin_amdgcn_mfma_f32_16x16x32_bf16(a0, b0, acc[0][0], 0, 0, 0);
        acc[0][1] = __builtin_amdgcn_mfma_f32_16x16x32_bf16(a0, b1, acc[0][1], 0, 0, 0);
        acc[1][0] = __builtin_amdgcn_mfma_f32_16x16x32_bf16(a1, b0, acc[1][0], 0, 0, 0);
        acc[1][1] = __builtin_amdgcn_mfma_f32_16x16x32_bf16(a1, b1, acc[1][1], 0, 0, 0);
      }
      __syncthreads();
    }
    int crow = (lane >> 4) * 4, ccol = lane & 15;  // C/D: col=lane&15, row=quad*4+reg [m89]
    #pragma unroll
    for (int i = 0; i < 2; i++)
      #pragma unroll
      for (int j = 0; j < 2; j++)
        #pragma unroll
        for (int e = 0; e < 4; e++){
          int r = row0 + wr*32 + i*16 + crow + e;
          int c = col0 + wc*32 + j*16 + ccol;
          P.G[(size_t)r * 512 + c] = f2bf(acc[i][j][e]);
        }
  }
  grid.sync();

  // ======================= P2: softmax(p)+agg1  ||  hop1 ====================
  {
    float* pb = (float*)smem;          // p[4096]
    float mx = -INFINITY;
    for (int i = tid; i < NNODE; i += NT) mx = fmaxf(mx, P.dstv[i]);
    #pragma unroll
    for (int o = 32; o >= 1; o >>= 1) mx = fmaxf(mx, __shfl_xor(mx, o, 64));
    if (lane == 0) red[wv] = mx;
    __syncthreads();
    mx = red[0];
    #pragma unroll
    for (int i = 1; i < 8; i++) mx = fmaxf(mx, red[i]);
    __syncthreads();
    float sum = 0.f;
    for (int i = tid; i < NNODE; i += NT){ float e = expf(P.dstv[i] - mx); pb[i] = e; sum += e; }
    #pragma unroll
    for (int o = 32; o >= 1; o >>= 1) sum += __shfl_xor(sum, o, 64);
    if (lane == 0) red[wv] = sum;
    __syncthreads();
    float tot = 0.f;
    #pragma unroll
    for (int i = 0; i < 8; i++) tot += red[i];
    float inv = 1.0f / tot;
    for (int i = tid; i < NNODE; i += NT) pb[i] *= inv;
    __syncthreads();

    // agg1: h1=elu(sum p[j] h[j,:]), h2 = h1.W2   (8 lanes/row, waves 0-1)
    if (tid < 128){
      int f = tid & 7, rg = tid >> 3;   // rg in [0,16)
      int row = rowBase + rg;
      const int* cl = P.cols + (size_t)row * CAP;
      int d = P.deg[row];
      float a = 0.f;
      for (int n = 0; n < d; n++){
        int j = cl[n];
        a += pb[j] * P.h[(size_t)j * HID + f];
      }
      float e = a > 0.f ? a : expm1f(a);
      float t = e * P.W2[f];
      t += __shfl_xor(t, 1, 64);
      t += __shfl_xor(t, 2, 64);
      t += __shfl_xor(t, 4, 64);
      if (f == 0) P.h2[row] = t;
    }
    // hop1: T1 = adj @ G_right (bf16), wave per row
    for (int rr = 0; rr < 2; rr++){
      int row = rowBase + wv * 2 + rr;
      f32x4 a = gather_row(P.G + 256, 512, P.cols + (size_t)row * CAP, P.deg[row], lane);
      store_bf4(P.T1 + (size_t)row * 256 + lane * 4, a);
    }
  }
  grid.sync();

  // ======================= P3: softmax(q)+mask  ||  hop2 ====================
  {
    float* pb = (float*)smem;          // q[4096]
    float s2 = P.a2[1];
    float mx = -INFINITY;
    for (int i = tid; i < NNODE; i += NT) mx = fmaxf(mx, s2 * P.h2[i]);
    #pragma unroll
    for (int o = 32; o >= 1; o >>= 1) mx = fmaxf(mx, __shfl_xor(mx, o, 64));
    if (lane == 0) red[wv] = mx;
    __syncthreads();
    mx = red[0];
    #pragma unroll
    for (int i = 1; i < 8; i++) mx = fmaxf(mx, red[i]);
    __syncthreads();
    float sum = 0.f;
    for (int i = tid; i < NNODE; i += NT){ float e = expf(s2 * P.h2[i] - mx); pb[i] = e; sum += e; }
    #pragma unroll
    for (int o = 32; o >= 1; o >>= 1) sum += __shfl_xor(sum, o, 64);
    if (lane == 0) red[wv] = sum;
    __syncthreads();
    float tot = 0.f;
    #pragma unroll
    for (int i = 0; i < 8; i++) tot += red[i];
    float inv = 1.0f / tot;
    for (int i = tid; i < NNODE; i += NT) pb[i] = pb[i] * inv * P.h2[i];
    __syncthreads();

    // mask for this block's 16 rows (LDS gather, trivial)
    if (tid < 16){
      int row = rowBase + tid;
      const int* cl = P.cols + (size_t)row * CAP;
      int d = P.deg[row];
      float s = 0.f;
      for (int n = 0; n < d; n++) s += pb[cl[n]];
      float e = s > 0.f ? s : expm1f(s);
      P.maskf[row] = (e > 0.7f) ? 1.0f : 0.0f;
    }
    // hop2: T2 = adj @ T1 (bf16)
    for (int rr = 0; rr < 2; rr++){
      int row = rowBase + wv * 2 + rr;
      f32x4 a = gather_row(P.T1, 256, P.cols + (size_t)row * CAP, P.deg[row], lane);
      store_bf4(P.T2 + (size_t)row * 256 + lane * 4, a);
    }
  }
  grid.sync();

  // ======================= P4: pruned final hop + epilogue ==================
  for (int rr = 0; rr < 2; rr++){
    int row = rowBase + wv * 2 + rr;
    bool m = P.maskf[row] != 0.0f;     // wave-uniform
    const unsigned short* src = m ? P.G : P.T2;   // G left half (cols 0..255)
    int stride = m ? 512 : 256;
    f32x4 a = gather_row(src, stride, P.cols + (size_t)row * CAP, P.deg[row], lane);
    float4 bias = ((const float4*)P.bsgc)[lane];
    float4 o;
    o.x = a[0] + bias.x; o.y = a[1] + bias.y; o.z = a[2] + bias.z; o.w = a[3] + bias.w;
    ((float4*)(P.out + (size_t)row * OUTF))[lane] = o;
  }
}

extern "C" void kernel_launch(void* const* d_in, const int* in_sizes, int n_in,
                              void* d_out, int out_size, void* d_ws, size_t ws_size,
                              hipStream_t stream) {
  KParams P;
  P.x    = (const float*)d_in[0];
  P.adj  = (const float*)d_in[1];
  P.W1   = (const float*)d_in[2];
  P.a1   = (const float*)d_in[3];
  P.W2   = (const float*)d_in[4];
  P.a2   = (const float*)d_in[5];
  P.Wsgc = (const float*)d_in[6];
  P.bsgc = (const float*)d_in[7];
  P.out  = (float*)d_out;

  char* w = (char*)d_ws;
  size_t off = 0;
  auto carve = [&](size_t bytes) -> char* {
    char* p = w + off;
    off += (bytes + 255) & ~(size_t)255;
    return p;
  };
  P.deg   = (int*)carve((size_t)NNODE * 4);
  P.cols  = (int*)carve((size_t)NNODE * CAP * 4);
  P.h     = (float*)carve((size_t)NNODE * HID * 4);
  P.dstv  = (float*)carve((size_t)NNODE * 4);
  P.h2    = (float*)carve((size_t)NNODE * 4);
  P.maskf = (float*)carve((size_t)NNODE * 4);
  P.xb    = (unsigned short*)carve((size_t)NNODE * INF * 2);
  P.wbT   = (unsigned short*)carve((size_t)512 * 512 * 2);
  P.G     = (unsigned short*)carve((size_t)NNODE * 512 * 2);
  P.T1    = (unsigned short*)carve((size_t)NNODE * OUTF * 2);
  P.T2    = (unsigned short*)carve((size_t)NNODE * OUTF * 2);

  void* args[] = { &P };
  hipLaunchCooperativeKernel((const void*)fused_all, dim3(NB), dim3(NT), args, 0, stream);
}

// Round 4
// 241.247 us; speedup vs baseline: 1.3573x; 1.3573x over previous
//
#include <hip/hip_runtime.h>
#include <hip/hip_bf16.h>
#include <cstddef>

#define NNODE 4096
#define INF   512
#define OUTF  256
#define HID   8
#define CAP   128   // max degree; Binomial(4096,0.01) max ~67
#define NB    256   // 1 block per CU (cooperative launch guarantees co-residency)
#define NT    1024  // 16 waves per block -> 16 waves/CU

typedef __attribute__((ext_vector_type(8))) short short8;
typedef __attribute__((ext_vector_type(4))) float f32x4;

__device__ __forceinline__ unsigned short f2bf(float f){
  unsigned int u = __float_as_uint(f);
  u += 0x7fffu + ((u >> 16) & 1u);   // RNE
  return (unsigned short)(u >> 16);
}
__device__ __forceinline__ float bf2f(unsigned short s){
  return __uint_as_float(((unsigned int)s) << 16);
}

struct KParams {
  const float* x; const float* adj; const float* W1; const float* a1;
  const float* W2; const float* a2; const float* Wsgc; const float* bsgc;
  float* out;
  int* bar;                      // [0]=cnt, [32]=gen (zeroed by memsetAsync)
  int* deg; int* cols; float* h; float* dstv; float* h2; float* maskf;
  unsigned short* xb; unsigned short* wbT; unsigned short* G;
  unsigned short* T1; unsigned short* T2;
};

// fast grid barrier: agent-scope atomics, relaxed spin + s_sleep, sense = gen counter.
// ~3 us for 256 blocks vs ~40 us for cg::grid.sync()'s backoff implementation.
__device__ __forceinline__ void gbar(int* bar){
  __syncthreads();
  if (threadIdx.x == 0){
    int* cnt = bar;
    int* gen = bar + 32;
    int g = __hip_atomic_load(gen, __ATOMIC_RELAXED, __HIP_MEMORY_SCOPE_AGENT);
    int a = __hip_atomic_fetch_add(cnt, 1, __ATOMIC_ACQ_REL, __HIP_MEMORY_SCOPE_AGENT);
    if (a == NB - 1){
      __hip_atomic_store(cnt, 0, __ATOMIC_RELAXED, __HIP_MEMORY_SCOPE_AGENT);
      __hip_atomic_fetch_add(gen, 1, __ATOMIC_RELEASE, __HIP_MEMORY_SCOPE_AGENT);
    } else {
      while (__hip_atomic_load(gen, __ATOMIC_RELAXED, __HIP_MEMORY_SCOPE_AGENT) == g){
        __builtin_amdgcn_s_sleep(8);
      }
      __threadfence();   // acquire: invalidate stale L1/L2 before reading peers' data
    }
  }
  __syncthreads();
}

// gather sum of bf16 row-segments (4 cols per lane), unroll-8 for MLP
__device__ __forceinline__ f32x4 gather_row(const unsigned short* __restrict__ src,
                                            int stride, const int* __restrict__ cl,
                                            int d, int lane){
  f32x4 acc = {0.f, 0.f, 0.f, 0.f};
  int n = 0;
  for (; n + 8 <= d; n += 8){
    ushort4 v[8];
    #pragma unroll
    for (int u = 0; u < 8; u++){
      int j = cl[n + u];
      v[u] = *(const ushort4*)(src + (size_t)j * stride + lane * 4);
    }
    #pragma unroll
    for (int u = 0; u < 8; u++){
      acc[0] += bf2f(v[u].x); acc[1] += bf2f(v[u].y);
      acc[2] += bf2f(v[u].z); acc[3] += bf2f(v[u].w);
    }
  }
  for (; n < d; n++){
    int j = cl[n];
    ushort4 vv = *(const ushort4*)(src + (size_t)j * stride + lane * 4);
    acc[0] += bf2f(vv.x); acc[1] += bf2f(vv.y); acc[2] += bf2f(vv.z); acc[3] += bf2f(vv.w);
  }
  return acc;
}

__global__ __launch_bounds__(NT, 4) void fused_all(KParams P){
  __shared__ __align__(16) char smem[44032];  // tiles 27648 + pb 16384
  __shared__ float red[16];
  __shared__ int cnts[16];
  const int tid = threadIdx.x, lane = tid & 63, wv = tid >> 6;
  const int b = blockIdx.x, rowBase = b * 16;
  const int myrow = rowBase + wv;            // this wave's row, all phases
  float* pb = (float*)(smem + 27648);

  // ======================= P0: converts + gat_h + CSR =======================
  if (tid < 16) cnts[tid] = 0;
  __syncthreads();

  { // W' -> bf16 transposed: wbT[c*512+k]; c<256 -> Wsgc[k][c], else Wsgc[1024+k][c-256]
    int e = b * NT + tid;                    // 262144 = NB*NT exactly
    int c = e >> 9, k = e & 511;
    float val = (c < OUTF) ? P.Wsgc[(size_t)k * OUTF + c]
                           : P.Wsgc[(size_t)(1024 + k) * OUTF + (c - OUTF)];
    P.wbT[e] = f2bf(val);
  }
  { // gat_h fused with x->bf16: h = x@W1, dstv = h . a1[8:16]
    const float* xr = P.x + (size_t)myrow * INF;
    unsigned short* xbr = P.xb + (size_t)myrow * INF;
    float acc[HID];
    #pragma unroll
    for (int f = 0; f < HID; f++) acc[f] = 0.f;
    #pragma unroll
    for (int kk = 0; kk < 8; kk++){
      int k = kk * 64 + lane;
      float xv = xr[k];
      xbr[k] = f2bf(xv);                     // 128B coalesced per iter
      const float* wp = P.W1 + (size_t)k * HID;
      #pragma unroll
      for (int f = 0; f < HID; f++) acc[f] += xv * wp[f];
    }
    #pragma unroll
    for (int f = 0; f < HID; f++)
      for (int o = 32; o >= 1; o >>= 1) acc[f] += __shfl_xor(acc[f], o, 64);
    if (lane == 0){
      float d = 0.f;
      #pragma unroll
      for (int f = 0; f < HID; f++){ P.h[(size_t)myrow*HID + f] = acc[f]; d += acc[f] * P.a1[HID + f]; }
      P.dstv[myrow] = d;
    }
  }
  { // CSR: wave scans its row (neighbor order irrelevant: all consumers sum)
    const float4* arow = (const float4*)(P.adj + (size_t)myrow * NNODE);
    int* crow = P.cols + (size_t)myrow * CAP;
    for (int kk = 0; kk < 16; kk++){
      int idx = kk * 64 + lane;
      float4 v = arow[idx];
      int n0=(v.x!=0.f), n1=(v.y!=0.f), n2=(v.z!=0.f), n3=(v.w!=0.f);
      int m = n0 + n1 + n2 + n3;
      if (m){
        int base = atomicAdd(&cnts[wv], m);
        int c = idx * 4;
        if (n0){ if (base < CAP) crow[base] = c;     base++; }
        if (n1){ if (base < CAP) crow[base] = c + 1; base++; }
        if (n2){ if (base < CAP) crow[base] = c + 2; base++; }
        if (n3){ if (base < CAP) crow[base] = c + 3; }
      }
    }
  }
  __syncthreads();
  if (tid < 16) P.deg[rowBase + tid] = cnts[tid] > CAP ? CAP : cnts[tid];
  gbar(P.bar);

  // ======================= P1: softmax(p) + GEMM + agg1 =====================
  { // p = softmax(dstv) into LDS (redundant per block; dstv is 16KB, L2-hot)
    float mx = -INFINITY;
    for (int i = tid; i < NNODE; i += NT) mx = fmaxf(mx, P.dstv[i]);
    #pragma unroll
    for (int o = 32; o >= 1; o >>= 1) mx = fmaxf(mx, __shfl_xor(mx, o, 64));
    if (lane == 0) red[wv] = mx;
    __syncthreads();
    mx = red[0];
    #pragma unroll
    for (int i = 1; i < 16; i++) mx = fmaxf(mx, red[i]);
    __syncthreads();
    float sum = 0.f;
    for (int i = tid; i < NNODE; i += NT){ float e = expf(P.dstv[i] - mx); pb[i] = e; sum += e; }
    #pragma unroll
    for (int o = 32; o >= 1; o >>= 1) sum += __shfl_xor(sum, o, 64);
    if (lane == 0) red[wv] = sum;
    __syncthreads();
    float tot = 0.f;
    #pragma unroll
    for (int i = 0; i < 16; i++) tot += red[i];
    float inv = 1.0f / tot;
    for (int i = tid; i < NNODE; i += NT) pb[i] *= inv;
    __syncthreads();
  }
  { // GEMM G = xb @ W' (bf16 MFMA). 256 tiles of 128x64; 16 waves in 4x4,
    // each wave 32 rows x 16 cols (2 MFMAs of 16x16x32 per kk)
    unsigned short (*As)[72] = (unsigned short (*)[72])smem;
    unsigned short (*Bs)[72] = (unsigned short (*)[72])(smem + 128*72*2);
    int row0 = (b >> 3) * 128;
    int col0 = (b & 7) * 64;
    int wr = wv >> 2, wc = wv & 3;
    f32x4 acc0 = {0.f,0.f,0.f,0.f}, acc1 = {0.f,0.f,0.f,0.f};
    int mrow = lane & 15;
    int kq = (lane >> 4) * 8;
    for (int k0 = 0; k0 < 512; k0 += 64){
      { int r = tid >> 3, ko = (tid & 7) * 8;   // A: 1024 int4 / 1024 thr
        *(int4*)(&As[r][ko]) = *(const int4*)(P.xb + (size_t)(row0 + r) * 512 + k0 + ko); }
      if (tid < 512){                            // B: 512 int4
        int c = tid >> 3, ko = (tid & 7) * 8;
        *(int4*)(&Bs[c][ko]) = *(const int4*)(P.wbT + (size_t)(col0 + c) * 512 + k0 + ko); }
      __syncthreads();
      #pragma unroll
      for (int kk = 0; kk < 2; kk++){
        short8 a0 = *(const short8*)(&As[wr*32 +  0 + mrow][kk*32 + kq]);
        short8 a1 = *(const short8*)(&As[wr*32 + 16 + mrow][kk*32 + kq]);
        short8 b0 = *(const short8*)(&Bs[wc*16 + mrow][kk*32 + kq]);
        acc0 = __builtin_amdgcn_mfma_f32_16x16x32_bf16(a0, b0, acc0, 0, 0, 0);
        acc1 = __builtin_amdgcn_mfma_f32_16x16x32_bf16(a1, b0, acc1, 0, 0, 0);
      }
      __syncthreads();
    }
    int crow = (lane >> 4) * 4, ccol = lane & 15;  // C/D: col=lane&15, row=quad*4+reg [m89]
    int c = col0 + wc*16 + ccol;
    #pragma unroll
    for (int e = 0; e < 4; e++){
      P.G[(size_t)(row0 + wr*32 +  0 + crow + e) * 512 + c] = f2bf(acc0[e]);
      P.G[(size_t)(row0 + wr*32 + 16 + crow + e) * 512 + c] = f2bf(acc1[e]);
    }
  }
  __syncthreads();
  { // agg1: h1 = elu(sum_j p[j] h[j,:]), h2 = h1.W2.  wave per row,
    // lane = part*8 + f: parts stride neighbors, xor-reduce 8/16/32 then 1/2/4
    int f = lane & 7, part = lane >> 3;
    const int* cl = P.cols + (size_t)myrow * CAP;
    int d = P.deg[myrow];
    float a = 0.f;
    for (int n = part; n < d; n += 8){
      int j = cl[n];
      a += pb[j] * P.h[(size_t)j * HID + f];
    }
    a += __shfl_xor(a, 8, 64); a += __shfl_xor(a, 16, 64); a += __shfl_xor(a, 32, 64);
    float e = a > 0.f ? a : expm1f(a);
    float t = e * P.W2[f];
    t += __shfl_xor(t, 1, 64); t += __shfl_xor(t, 2, 64); t += __shfl_xor(t, 4, 64);
    if (lane == 0) P.h2[myrow] = t;
  }
  gbar(P.bar);

  // ======================= P2: softmax(q)+mask + hop1 =======================
  { // q[j] = softmax(a2[1]*h2)[j] * h2[j] into LDS
    float s2 = P.a2[1];
    float mx = -INFINITY;
    for (int i = tid; i < NNODE; i += NT) mx = fmaxf(mx, s2 * P.h2[i]);
    #pragma unroll
    for (int o = 32; o >= 1; o >>= 1) mx = fmaxf(mx, __shfl_xor(mx, o, 64));
    if (lane == 0) red[wv] = mx;
    __syncthreads();
    mx = red[0];
    #pragma unroll
    for (int i = 1; i < 16; i++) mx = fmaxf(mx, red[i]);
    __syncthreads();
    float sum = 0.f;
    for (int i = tid; i < NNODE; i += NT){ float e = expf(s2 * P.h2[i] - mx); pb[i] = e; sum += e; }
    #pragma unroll
    for (int o = 32; o >= 1; o >>= 1) sum += __shfl_xor(sum, o, 64);
    if (lane == 0) red[wv] = sum;
    __syncthreads();
    float tot = 0.f;
    #pragma unroll
    for (int i = 0; i < 16; i++) tot += red[i];
    float inv = 1.0f / tot;
    for (int i = tid; i < NNODE; i += NT) pb[i] = pb[i] * inv * P.h2[i];
    __syncthreads();
  }
  { // mask: wave per row, LDS gather + reduce
    const int* cl = P.cols + (size_t)myrow * CAP;
    int d = P.deg[myrow];
    float s = 0.f;
    for (int n = lane; n < d; n += 64) s += pb[cl[n]];
    #pragma unroll
    for (int o = 32; o >= 1; o >>= 1) s += __shfl_xor(s, o, 64);
    if (lane == 0){
      float e = s > 0.f ? s : expm1f(s);
      P.maskf[myrow] = (e > 0.7f) ? 1.0f : 0.0f;
    }
  }
  { // hop1: T1 = adj @ G_right
    f32x4 a = gather_row(P.G + 256, 512, P.cols + (size_t)myrow * CAP, P.deg[myrow], lane);
    union { ushort4 v; unsigned short u[4]; } o;
    o.u[0]=f2bf(a[0]); o.u[1]=f2bf(a[1]); o.u[2]=f2bf(a[2]); o.u[3]=f2bf(a[3]);
    *(ushort4*)(P.T1 + (size_t)myrow * 256 + lane * 4) = o.v;
  }
  gbar(P.bar);

  // ======================= P3: hop2 + final for mask=1 rows =================
  {
    f32x4 a = gather_row(P.T1, 256, P.cols + (size_t)myrow * CAP, P.deg[myrow], lane);
    union { ushort4 v; unsigned short u[4]; } o;
    o.u[0]=f2bf(a[0]); o.u[1]=f2bf(a[1]); o.u[2]=f2bf(a[2]); o.u[3]=f2bf(a[3]);
    *(ushort4*)(P.T2 + (size_t)myrow * 256 + lane * 4) = o.v;
    if (P.maskf[myrow] != 0.0f){             // wave-uniform
      f32x4 s = gather_row(P.G, 512, P.cols + (size_t)myrow * CAP, P.deg[myrow], lane);
      float4 bias = ((const float4*)P.bsgc)[lane];
      float4 ov; ov.x = s[0]+bias.x; ov.y = s[1]+bias.y; ov.z = s[2]+bias.z; ov.w = s[3]+bias.w;
      ((float4*)(P.out + (size_t)myrow * OUTF))[lane] = ov;
    }
  }
  gbar(P.bar);

  // ======================= P4: final for mask=0 rows ========================
  if (P.maskf[myrow] == 0.0f){
    f32x4 s = gather_row(P.T2, 256, P.cols + (size_t)myrow * CAP, P.deg[myrow], lane);
    float4 bias = ((const float4*)P.bsgc)[lane];
    float4 ov; ov.x = s[0]+bias.x; ov.y = s[1]+bias.y; ov.z = s[2]+bias.z; ov.w = s[3]+bias.w;
    ((float4*)(P.out + (size_t)myrow * OUTF))[lane] = ov;
  }
}

extern "C" void kernel_launch(void* const* d_in, const int* in_sizes, int n_in,
                              void* d_out, int out_size, void* d_ws, size_t ws_size,
                              hipStream_t stream) {
  KParams P;
  P.x    = (const float*)d_in[0];
  P.adj  = (const float*)d_in[1];
  P.W1   = (const float*)d_in[2];
  P.a1   = (const float*)d_in[3];
  P.W2   = (const float*)d_in[4];
  P.a2   = (const float*)d_in[5];
  P.Wsgc = (const float*)d_in[6];
  P.bsgc = (const float*)d_in[7];
  P.out  = (float*)d_out;

  char* w = (char*)d_ws;
  size_t off = 0;
  auto carve = [&](size_t bytes) -> char* {
    char* p = w + off;
    off += (bytes + 255) & ~(size_t)255;
    return p;
  };
  P.bar   = (int*)carve(256);                // must be first; zeroed below
  P.deg   = (int*)carve((size_t)NNODE * 4);
  P.cols  = (int*)carve((size_t)NNODE * CAP * 4);
  P.h     = (float*)carve((size_t)NNODE * HID * 4);
  P.dstv  = (float*)carve((size_t)NNODE * 4);
  P.h2    = (float*)carve((size_t)NNODE * 4);
  P.maskf = (float*)carve((size_t)NNODE * 4);
  P.xb    = (unsigned short*)carve((size_t)NNODE * INF * 2);
  P.wbT   = (unsigned short*)carve((size_t)512 * 512 * 2);
  P.G     = (unsigned short*)carve((size_t)NNODE * 512 * 2);
  P.T1    = (unsigned short*)carve((size_t)NNODE * OUTF * 2);
  P.T2    = (unsigned short*)carve((size_t)NNODE * OUTF * 2);

  hipMemsetAsync(P.bar, 0, 256, stream);     // barrier state (d_ws is poisoned 0xAA)

  void* args[] = { &P };
  hipLaunchCooperativeKernel((const void*)fused_all, dim3(NB), dim3(NT), args, 0, stream);
}

// Round 6
// 218.724 us; speedup vs baseline: 1.4971x; 1.1030x over previous
//
#include <hip/hip_runtime.h>
#include <hip/hip_bf16.h>
#include <cstddef>

#define NNODE 4096
#define INF   512
#define OUTF  256
#define HID   8
#define CAP   128   // max degree; Binomial(4096,0.01) max ~67
#define NB    256   // 1 block/CU — the proven cooperative-launchable shape
#define NT    1024  // 16 waves/block
#define RPB   16    // rows per block

typedef __attribute__((ext_vector_type(8))) short short8;
typedef __attribute__((ext_vector_type(4))) float f32x4;

__device__ __forceinline__ unsigned short f2bf(float f){
  unsigned int u = __float_as_uint(f);
  u += 0x7fffu + ((u >> 16) & 1u);   // RNE
  return (unsigned short)(u >> 16);
}
__device__ __forceinline__ float bf2f(unsigned short s){
  return __uint_as_float(((unsigned int)s) << 16);
}

struct KParams {
  const float* x; const float* adj; const float* W1; const float* a1;
  const float* W2; const float* a2; const float* Wsgc; const float* bsgc;
  float* out;
  int* bar;                      // [0]=cnt, [32]=gen (zeroed by memsetAsync)
  float* h; float* dstv; float* h2;
  unsigned short* G; unsigned short* T1; unsigned short* T2;
};

// fast grid barrier: agent-scope atomics, relaxed spin + s_sleep (proven R4).
__device__ __forceinline__ void gbar(int* bar){
  __syncthreads();
  if (threadIdx.x == 0){
    int* cnt = bar;
    int* gen = bar + 32;
    int g = __hip_atomic_load(gen, __ATOMIC_RELAXED, __HIP_MEMORY_SCOPE_AGENT);
    int a = __hip_atomic_fetch_add(cnt, 1, __ATOMIC_ACQ_REL, __HIP_MEMORY_SCOPE_AGENT);
    if (a == NB - 1){
      __hip_atomic_store(cnt, 0, __ATOMIC_RELAXED, __HIP_MEMORY_SCOPE_AGENT);
      __hip_atomic_fetch_add(gen, 1, __ATOMIC_RELEASE, __HIP_MEMORY_SCOPE_AGENT);
    } else {
      while (__hip_atomic_load(gen, __ATOMIC_RELAXED, __HIP_MEMORY_SCOPE_AGENT) == g){
        __builtin_amdgcn_s_sleep(8);
      }
      __threadfence();   // acquire side: see peers' global writes
    }
  }
  __syncthreads();
}

// gather sum of bf16 row-segments (4 cols per lane), 8 independent loads/batch
__device__ __forceinline__ f32x4 gather_row(const unsigned short* __restrict__ src,
                                            int stride, const int* __restrict__ cl,
                                            int d, int lane){
  f32x4 acc = {0.f, 0.f, 0.f, 0.f};
  int n = 0;
  for (; n + 8 <= d; n += 8){
    ushort4 v[8];
    #pragma unroll
    for (int u = 0; u < 8; u++){
      int j = cl[n + u];
      v[u] = *(const ushort4*)(src + (size_t)j * stride + lane * 4);
    }
    #pragma unroll
    for (int u = 0; u < 8; u++){
      acc[0] += bf2f(v[u].x); acc[1] += bf2f(v[u].y);
      acc[2] += bf2f(v[u].z); acc[3] += bf2f(v[u].w);
    }
  }
  for (; n < d; n++){
    int j = cl[n];
    ushort4 vv = *(const ushort4*)(src + (size_t)j * stride + lane * 4);
    acc[0] += bf2f(vv.x); acc[1] += bf2f(vv.y); acc[2] += bf2f(vv.z); acc[3] += bf2f(vv.w);
  }
  return acc;
}

__global__ __launch_bounds__(NT, 4) void fused_all(KParams P){
  __shared__ __align__(16) char smem[27648]; // P0: As 18432 + Bs 9216; P1+: pb 16384
  __shared__ int   colsL[RPB][CAP];          // 8 KB: CSR lists, block-local all phases
  __shared__ int   cnts[RPB];
  __shared__ int   degL[RPB];
  __shared__ float maskL[RPB];
  __shared__ float red[16];
  const int tid = threadIdx.x, lane = tid & 63, wv = tid >> 6;
  const int b = blockIdx.x, rowBase = b * RPB;
  const int myrow = rowBase + wv;            // this wave's row in per-row phases
  float* pb = (float*)smem;

  // ======================= P0: CSR + gat_h + GEMM ==========================
  if (tid < RPB) cnts[tid] = 0;
  __syncthreads();

  { // CSR, strip-mined: wave wv scans cols [wv*256, wv*256+256) of ALL 16 rows.
    // 2 batches of 8 independent coalesced float4 loads -> ~2 stall windows.
    int cbase = wv * 256 + lane * 4;
    #pragma unroll
    for (int hf = 0; hf < 2; hf++){
      float4 v[8];
      #pragma unroll
      for (int r = 0; r < 8; r++)
        v[r] = *(const float4*)(P.adj + (size_t)(rowBase + hf * 8 + r) * NNODE + cbase);
      #pragma unroll
      for (int r = 0; r < 8; r++){
        int rr = hf * 8 + r;
        int n0=(v[r].x!=0.f), n1=(v[r].y!=0.f), n2=(v[r].z!=0.f), n3=(v[r].w!=0.f);
        int m = n0 + n1 + n2 + n3;
        if (m){
          int base = atomicAdd(&cnts[rr], m);
          if (n0){ if (base < CAP) colsL[rr][base] = cbase;     base++; }
          if (n1){ if (base < CAP) colsL[rr][base] = cbase + 1; base++; }
          if (n2){ if (base < CAP) colsL[rr][base] = cbase + 2; base++; }
          if (n3){ if (base < CAP) colsL[rr][base] = cbase + 3; }
        }
      }
    }
  }
  { // gat_h: h = x@W1, dstv = h . a1[8:16]  (fp32, wave per row)
    const float* xr = P.x + (size_t)myrow * INF;
    float acc[HID];
    #pragma unroll
    for (int f = 0; f < HID; f++) acc[f] = 0.f;
    #pragma unroll
    for (int kk = 0; kk < 8; kk++){
      int k = kk * 64 + lane;
      float xv = xr[k];
      const float* wp = P.W1 + (size_t)k * HID;
      #pragma unroll
      for (int f = 0; f < HID; f++) acc[f] += xv * wp[f];
    }
    #pragma unroll
    for (int f = 0; f < HID; f++)
      for (int o = 32; o >= 1; o >>= 1) acc[f] += __shfl_xor(acc[f], o, 64);
    if (lane == 0){
      float d = 0.f;
      #pragma unroll
      for (int f = 0; f < HID; f++){ P.h[(size_t)myrow*HID + f] = acc[f]; d += acc[f] * P.a1[HID + f]; }
      P.dstv[myrow] = d;
    }
  }
  __syncthreads();
  if (tid < RPB) degL[tid] = cnts[tid] > CAP ? CAP : cnts[tid];
  { // GEMM G = bf16(x) @ W' — R4's proven 128x64 tile / fragment indexing,
    // but A and B converted fp32->bf16 in flight (no xb/wbT buffers).
    unsigned short (*As)[72] = (unsigned short (*)[72])smem;           // 128 x 64 (+8)
    unsigned short (*Bs)[72] = (unsigned short (*)[72])(smem + 18432); // 64 x 64 (+8)
    int row0 = (b >> 3) * 128;
    int col0 = (b & 7) * 64;
    int col0c = col0 & 255;
    int kb = (col0 >= 256) ? 1024 : 0;  // W'[k][c<256]=Wsgc[k][c]; else Wsgc[1024+k][c-256]
    int wr = wv >> 2, wc = wv & 3;      // 4x4 waves: 32 rows x 16 cols each
    f32x4 acc0 = {0.f,0.f,0.f,0.f}, acc1 = {0.f,0.f,0.f,0.f};
    int mrow = lane & 15;
    int kq = (lane >> 4) * 8;
    int ar = tid >> 3, ako = (tid & 7) * 8;       // A: 128 rows x 8 chunks
    int bc = tid & 63, bk8 = (tid >> 6) * 8;      // B (tid<512): 64 cols x 8 k-chunks
    for (int k0 = 0; k0 < 512; k0 += 64){
      { // A: x[row0+ar][k0+ako..+7] -> bf16 -> As[ar][ako]
        const float* src = P.x + (size_t)(row0 + ar) * INF + k0 + ako;
        float4 v0 = ((const float4*)src)[0];
        float4 v1 = ((const float4*)src)[1];
        union { short8 v; unsigned short u[8]; } pk;
        pk.u[0]=f2bf(v0.x); pk.u[1]=f2bf(v0.y); pk.u[2]=f2bf(v0.z); pk.u[3]=f2bf(v0.w);
        pk.u[4]=f2bf(v1.x); pk.u[5]=f2bf(v1.y); pk.u[6]=f2bf(v1.z); pk.u[7]=f2bf(v1.w);
        *(short8*)(&As[ar][ako]) = pk.v;
      }
      if (tid < 512){ // B: Wsgc[kb+k0+bk8+i][col0c+bc] -> Bs[bc][bk8..+7]
        union { short8 v; unsigned short u[8]; } pk;
        #pragma unroll
        for (int i = 0; i < 8; i++)
          pk.u[i] = f2bf(P.Wsgc[(size_t)(kb + k0 + bk8 + i) * OUTF + col0c + bc]);
        *(short8*)(&Bs[bc][bk8]) = pk.v;
      }
      __syncthreads();
      #pragma unroll
      for (int kk = 0; kk < 2; kk++){
        short8 a0 = *(const short8*)(&As[wr*32 +  0 + mrow][kk*32 + kq]);
        short8 a1 = *(const short8*)(&As[wr*32 + 16 + mrow][kk*32 + kq]);
        short8 b0 = *(const short8*)(&Bs[wc*16 + mrow][kk*32 + kq]);
        acc0 = __builtin_amdgcn_mfma_f32_16x16x32_bf16(a0, b0, acc0, 0, 0, 0);
        acc1 = __builtin_amdgcn_mfma_f32_16x16x32_bf16(a1, b0, acc1, 0, 0, 0);
      }
      __syncthreads();
    }
    int crow = (lane >> 4) * 4, ccol = lane & 15;  // C/D: col=lane&15, row=quad*4+reg [m89]
    int c = col0 + wc*16 + ccol;
    #pragma unroll
    for (int e = 0; e < 4; e++){
      P.G[(size_t)(row0 + wr*32 +  0 + crow + e) * 512 + c] = f2bf(acc0[e]);
      P.G[(size_t)(row0 + wr*32 + 16 + crow + e) * 512 + c] = f2bf(acc1[e]);
    }
  }
  gbar(P.bar);

  // ======================= P1: softmax(p) + agg1 + hop1 =====================
  { // p = softmax(dstv) into LDS
    float mx = -INFINITY;
    for (int i = tid; i < NNODE; i += NT) mx = fmaxf(mx, P.dstv[i]);
    #pragma unroll
    for (int o = 32; o >= 1; o >>= 1) mx = fmaxf(mx, __shfl_xor(mx, o, 64));
    if (lane == 0) red[wv] = mx;
    __syncthreads();
    mx = red[0];
    #pragma unroll
    for (int i = 1; i < 16; i++) mx = fmaxf(mx, red[i]);
    __syncthreads();
    float sum = 0.f;
    for (int i = tid; i < NNODE; i += NT){ float e = expf(P.dstv[i] - mx); pb[i] = e; sum += e; }
    #pragma unroll
    for (int o = 32; o >= 1; o >>= 1) sum += __shfl_xor(sum, o, 64);
    if (lane == 0) red[wv] = sum;
    __syncthreads();
    float tot = 0.f;
    #pragma unroll
    for (int i = 0; i < 16; i++) tot += red[i];
    float inv = 1.0f / tot;
    for (int i = tid; i < NNODE; i += NT) pb[i] *= inv;
    __syncthreads();
  }
  { // agg1: h2 = (elu(sum_j p[j] h[j,:])) . W2 — wave per row, 8 partitions
    int f = lane & 7, part = lane >> 3;
    const int* cl = colsL[wv];
    int d = degL[wv];
    float a = 0.f;
    for (int n = part; n < d; n += 8){
      int j = cl[n];
      a += pb[j] * P.h[(size_t)j * HID + f];
    }
    a += __shfl_xor(a, 8, 64); a += __shfl_xor(a, 16, 64); a += __shfl_xor(a, 32, 64);
    float e = a > 0.f ? a : expm1f(a);
    float t = e * P.W2[f];
    t += __shfl_xor(t, 1, 64); t += __shfl_xor(t, 2, 64); t += __shfl_xor(t, 4, 64);
    if (lane == 0) P.h2[myrow] = t;
  }
  { // hop1: T1 = adj @ G_right
    f32x4 a = gather_row(P.G + 256, 512, colsL[wv], degL[wv], lane);
    union { ushort4 v; unsigned short u[4]; } o;
    o.u[0]=f2bf(a[0]); o.u[1]=f2bf(a[1]); o.u[2]=f2bf(a[2]); o.u[3]=f2bf(a[3]);
    *(ushort4*)(P.T1 + (size_t)myrow * 256 + lane * 4) = o.v;
  }
  gbar(P.bar);

  // ============== P2: softmax(q) + mask + hop2 + final(mask=1) ==============
  { // q[j] = softmax(a2[1]*h2)[j] * h2[j] into LDS
    float s2 = P.a2[1];
    float mx = -INFINITY;
    for (int i = tid; i < NNODE; i += NT) mx = fmaxf(mx, s2 * P.h2[i]);
    #pragma unroll
    for (int o = 32; o >= 1; o >>= 1) mx = fmaxf(mx, __shfl_xor(mx, o, 64));
    if (lane == 0) red[wv] = mx;
    __syncthreads();
    mx = red[0];
    #pragma unroll
    for (int i = 1; i < 16; i++) mx = fmaxf(mx, red[i]);
    __syncthreads();
    float sum = 0.f;
    for (int i = tid; i < NNODE; i += NT){ float e = expf(s2 * P.h2[i] - mx); pb[i] = e; sum += e; }
    #pragma unroll
    for (int o = 32; o >= 1; o >>= 1) sum += __shfl_xor(sum, o, 64);
    if (lane == 0) red[wv] = sum;
    __syncthreads();
    float tot = 0.f;
    #pragma unroll
    for (int i = 0; i < 16; i++) tot += red[i];
    float inv = 1.0f / tot;
    for (int i = tid; i < NNODE; i += NT) pb[i] = pb[i] * inv * P.h2[i];
    __syncthreads();
  }
  bool m1;
  { // mask: wave per row (all lanes learn it via the xor-reduce)
    const int* cl = colsL[wv];
    int d = degL[wv];
    float s = 0.f;
    for (int n = lane; n < d; n += 64) s += pb[cl[n]];
    #pragma unroll
    for (int o = 32; o >= 1; o >>= 1) s += __shfl_xor(s, o, 64);
    float e = s > 0.f ? s : expm1f(s);
    m1 = (e > 0.7f);
    if (lane == 0) maskL[wv] = m1 ? 1.0f : 0.0f;
  }
  { // hop2: T2 = adj @ T1
    f32x4 a = gather_row(P.T1, 256, colsL[wv], degL[wv], lane);
    union { ushort4 v; unsigned short u[4]; } o;
    o.u[0]=f2bf(a[0]); o.u[1]=f2bf(a[1]); o.u[2]=f2bf(a[2]); o.u[3]=f2bf(a[3]);
    *(ushort4*)(P.T2 + (size_t)myrow * 256 + lane * 4) = o.v;
  }
  if (m1){ // final for mask=1 rows: out = adj @ G_left + bias  (wave-uniform)
    f32x4 s = gather_row(P.G, 512, colsL[wv], degL[wv], lane);
    float4 bias = ((const float4*)P.bsgc)[lane];
    float4 ov; ov.x=s[0]+bias.x; ov.y=s[1]+bias.y; ov.z=s[2]+bias.z; ov.w=s[3]+bias.w;
    ((float4*)(P.out + (size_t)myrow * OUTF))[lane] = ov;
  }
  gbar(P.bar);

  // ======================= P3: final for mask=0 rows ========================
  if (maskL[wv] == 0.0f){                    // LDS persists across gbar
    f32x4 s = gather_row(P.T2, 256, colsL[wv], degL[wv], lane);
    float4 bias = ((const float4*)P.bsgc)[lane];
    float4 ov; ov.x=s[0]+bias.x; ov.y=s[1]+bias.y; ov.z=s[2]+bias.z; ov.w=s[3]+bias.w;
    ((float4*)(P.out + (size_t)myrow * OUTF))[lane] = ov;
  }
}

extern "C" void kernel_launch(void* const* d_in, const int* in_sizes, int n_in,
                              void* d_out, int out_size, void* d_ws, size_t ws_size,
                              hipStream_t stream) {
  KParams P;
  P.x    = (const float*)d_in[0];
  P.adj  = (const float*)d_in[1];
  P.W1   = (const float*)d_in[2];
  P.a1   = (const float*)d_in[3];
  P.W2   = (const float*)d_in[4];
  P.a2   = (const float*)d_in[5];
  P.Wsgc = (const float*)d_in[6];
  P.bsgc = (const float*)d_in[7];
  P.out  = (float*)d_out;

  char* w = (char*)d_ws;
  size_t off = 0;
  auto carve = [&](size_t bytes) -> char* {
    char* p = w + off;
    off += (bytes + 255) & ~(size_t)255;
    return p;
  };
  P.bar  = (int*)carve(256);
  P.h    = (float*)carve((size_t)NNODE * HID * 4);
  P.dstv = (float*)carve((size_t)NNODE * 4);
  P.h2   = (float*)carve((size_t)NNODE * 4);
  P.G    = (unsigned short*)carve((size_t)NNODE * 512 * 2);
  P.T1   = (unsigned short*)carve((size_t)NNODE * OUTF * 2);
  P.T2   = (unsigned short*)carve((size_t)NNODE * OUTF * 2);

  hipMemsetAsync(P.bar, 0, 256, stream);

  void* args[] = { &P };
  hipLaunchCooperativeKernel((const void*)fused_all, dim3(NB), dim3(NT), args, 0, stream);
}